// Round 8
// baseline (115.987 us; speedup 1.0000x reference)
//
#include <hip/hip_runtime.h>
#include <hip/hip_bf16.h>
#include <math.h>

// ---- problem constants ----
#define B_ROWS 512
#define D_K    512
#define C_CLS  100000

#define COS_M 0.8775825618903728f
#define SIN_M 0.479425538604203f
#define TH_C  (-0.8775825618903728f)    // cos(pi - m)
#define MM_C  0.2397127693021015f       // sin(pi - m) * m

#define LOG2E_S 92.33248261689366f      // 64 * log2(e)
#define M0      92.4f                   // fixed softmax bound: |cos|<=1 -> |L|<=92.33
#define LN2F    0.6931471805599453f

// ---- GEMM tile config ----
#define BN 64                           // classes per chunk
#define NCHUNK 1563                     // ceil(100000/64)
#define CPS 7                           // chunks per strip
#define NSTRIP 224                      // 224*7 = 1568 >= 1563; last strip 2 chunks

typedef __attribute__((ext_vector_type(4))) float f32x4;
typedef long long i64;

__device__ inline float fexp2(float x) {
#if __has_builtin(__builtin_amdgcn_exp2f)
    return __builtin_amdgcn_exp2f(x);
#else
    return exp2f(x);
#endif
}
#define LGKM0()  asm volatile("s_waitcnt lgkmcnt(0)" ::: "memory")
#define RAWBAR() __builtin_amdgcn_s_barrier()
#define SCHED0() __builtin_amdgcn_sched_barrier(0)

// ---------------- kernel 0: row-normalize -> fp8 e4m3 (x only) ----------------
__global__ __launch_bounds__(256) void rownorm8_kernel(const float* __restrict__ in,
                                                       uint2* __restrict__ out,
                                                       float* __restrict__ rnout,
                                                       int nvalid) {
    const int wid = threadIdx.x >> 6;
    const int lane = threadIdx.x & 63;
    const int r = blockIdx.x * 4 + wid;
    if (r >= nvalid) {
        out[(size_t)r * 64 + lane] = make_uint2(0u, 0u);
        return;
    }
    const float* row = in + (size_t)r * D_K + lane * 8;
    float4 a = *(const float4*)row;
    float4 b = *(const float4*)(row + 4);
    float ss = a.x * a.x + a.y * a.y + a.z * a.z + a.w * a.w
             + b.x * b.x + b.y * b.y + b.z * b.z + b.w * b.w;
    ss += __shfl_xor(ss, 1);  ss += __shfl_xor(ss, 2);  ss += __shfl_xor(ss, 4);
    ss += __shfl_xor(ss, 8);  ss += __shfl_xor(ss, 16); ss += __shfl_xor(ss, 32);
    const float rn = 1.0f / sqrtf(ss);
    int u0 = __builtin_amdgcn_cvt_pk_fp8_f32(a.x * rn, a.y * rn, 0, false);
    u0     = __builtin_amdgcn_cvt_pk_fp8_f32(a.z * rn, a.w * rn, u0, true);
    int u1 = __builtin_amdgcn_cvt_pk_fp8_f32(b.x * rn, b.y * rn, 0, false);
    u1     = __builtin_amdgcn_cvt_pk_fp8_f32(b.z * rn, b.w * rn, u1, true);
    out[(size_t)r * 64 + lane] = make_uint2((unsigned)u0, (unsigned)u1);
    if (rnout != nullptr && lane == 0) rnout[r] = rn;
}

// ---------------- kernel 1: single-pass fused strip GEMM ----------------
// One 512-thread block per strip. A (all 512 rows, fp8) in registers (128 VGPR/lane).
// Per kstep: issue slice k+4 fp32 loads; convert slice k+2 (raw fp8 quant, ss fold,
// swizzled ds_write_b64); lgkm0+barrier; 8 swizzled ds_read_b64 + 32 MFMA.
// rn reduced at k==5 from folded ss, applied post-dot inside exp2 at k==7.
__global__ __launch_bounds__(512, 2) void gemm_fused512_kernel(
        const unsigned char* __restrict__ xnb8,   // [512][512] fp8 normalized
        const float* __restrict__ w,              // [100000][512] fp32 raw
        float* __restrict__ partials) {           // [NSTRIP][512]
    const int t    = threadIdx.x;
    const int lane = t & 63;
    const int wid  = t >> 6;
    const int cl   = lane & 15;
    const int hi   = lane >> 4;

    const int s     = blockIdx.x;
    const int cbase = s * (CPS * BN);
    const int rem   = NCHUNK - s * CPS;
    const int nch   = rem < CPS ? rem : CPS;
    const int nst   = nch * 8;

    __shared__ char  smem[8 * 4096];   // fp8 B ring, 32 KB
    __shared__ float rnsh[64];

    // staging identity: thread t owns row t>>3 of the 64x64 slice, logical granule t&7
    const int sr  = t >> 3;
    const int gl  = t & 7;
    const int wrb = sr * 64 + ((gl ^ ((sr >> 1) & 7)) << 3);   // swizzled write byte

    // ---- prologue: issue fp32 loads for slices 0..3 ----
    float4 qa[4], qb[4];
#define LOADSL(sl, set)                                                          \
    {                                                                            \
        int _s = (sl) < nst ? (sl) : nst - 1;                                    \
        int _c = cbase + (_s >> 3) * 64 + sr;                                    \
        _c = _c < C_CLS ? _c : C_CLS - 1;                                        \
        const float* _p = w + (size_t)_c * D_K + (_s & 7) * 64 + gl * 8;         \
        qa[set] = *(const float4*)_p;                                            \
        qb[set] = *(const float4*)(_p + 4);                                      \
    }
#define CONVSL(sl, set, ssvar)                                                   \
    if ((sl) < nst) {                                                            \
        float4 _a = qa[set], _b = qb[set];                                       \
        ssvar += _a.x * _a.x + _a.y * _a.y + _a.z * _a.z + _a.w * _a.w           \
               + _b.x * _b.x + _b.y * _b.y + _b.z * _b.z + _b.w * _b.w;          \
        int _u0 = __builtin_amdgcn_cvt_pk_fp8_f32(_a.x, _a.y, 0, false);         \
        _u0     = __builtin_amdgcn_cvt_pk_fp8_f32(_a.z, _a.w, _u0, true);        \
        int _u1 = __builtin_amdgcn_cvt_pk_fp8_f32(_b.x, _b.y, 0, false);         \
        _u1     = __builtin_amdgcn_cvt_pk_fp8_f32(_b.z, _b.w, _u1, true);        \
        *(uint2*)(smem + ((sl) & 7) * 4096 + wrb) =                              \
            make_uint2((unsigned)_u0, (unsigned)_u1);                            \
    }

    LOADSL(0, 0)
    LOADSL(1, 1)
    LOADSL(2, 2)
    LOADSL(3, 3)

    // ---- A: 64 rows/wave, full K, fp8 in registers (xnb8 is L2/L3-resident) ----
    i64 a8[4][16];
#pragma unroll
    for (int m = 0; m < 4; ++m) {
        const unsigned char* ap =
            xnb8 + (size_t)(wid * 64 + m * 16 + cl) * 512 + hi * 8;
#pragma unroll
        for (int ks = 0; ks < 8; ++ks) {
#pragma unroll
            for (int kk = 0; kk < 2; ++kk)
                a8[m][ks * 2 + kk] = *(const i64*)(ap + ks * 64 + kk * 32);
        }
    }

    float ssCur = 0.f, ssNext = 0.f;
    CONVSL(0, 0, ssCur)
    CONVSL(1, 1, ssCur)
    LGKM0();
    RAWBAR();
    SCHED0();

    float sums[16];
#pragma unroll
    for (int i = 0; i < 16; ++i) sums[i] = 0.f;

    const int swzr = cl >> 1;   // read-side swizzle: ((n*16+cl)>>1)&7 == cl>>1

    for (int ci = 0; ci < nch; ++ci) {
        f32x4 acc[4][4];
#pragma unroll
        for (int m = 0; m < 4; ++m)
#pragma unroll
            for (int n = 0; n < 4; ++n) acc[m][n] = (f32x4){0.f, 0.f, 0.f, 0.f};

#pragma unroll
        for (int k = 0; k < 8; ++k) {
            // 1. issue loads for slice k+4 into regset k&3 ( == (k+4)&3 )
            LOADSL(ci * 8 + k + 4, (k) & 3)
            // 2. convert slice k+2 (loaded 2 ksteps ago) -> buffer (k+2)&7
            if (k < 6) {
                CONVSL(ci * 8 + k + 2, (k + 2) & 3, ssCur)
            } else {
                CONVSL(ci * 8 + k + 2, (k + 2) & 3, ssNext)
            }
            // 3. at k==5 this chunk's ss is complete -> rnorm to LDS
            if (k == 5) {
                float a = ssCur;
                a += __shfl_xor(a, 1);
                a += __shfl_xor(a, 2);
                a += __shfl_xor(a, 4);
                if ((lane & 7) == 0) {
                    const int c = cbase + ci * 64 + sr;
                    rnsh[sr] = (c < C_CLS) ? (1.0f / sqrtf(a)) : 0.0f;
                }
            }
            // 4. fence own LDS writes, rendezvous
            LGKM0();
            RAWBAR();
            SCHED0();
            // 5. B frags from buffer k (written 2 ksteps ago) + MFMA
            const char* sB = smem + (k & 7) * 4096;
#pragma unroll
            for (int kk = 0; kk < 2; ++kk) {
                i64 bfr[4];
#pragma unroll
                for (int n = 0; n < 4; ++n) {
                    const int row = n * 16 + cl;
                    const int pg  = (kk * 4 + hi) ^ swzr;
                    bfr[n] = *(const i64*)(sB + row * 64 + (pg << 3));
                }
#pragma unroll
                for (int m = 0; m < 4; ++m)
#pragma unroll
                    for (int n = 0; n < 4; ++n)
                        acc[m][n] = __builtin_amdgcn_mfma_f32_16x16x32_fp8_fp8(
                            a8[m][k * 2 + kk], bfr[n], acc[m][n], 0, 0, 0);
            }
            // 6. chunk epilogue: post-dot normalization inside fixed-M0 exp
            if (k == 7) {
                float rl[4];
#pragma unroll
                for (int n = 0; n < 4; ++n) rl[n] = rnsh[n * 16 + cl] * LOG2E_S;
#pragma unroll
                for (int m = 0; m < 4; ++m)
#pragma unroll
                    for (int jj = 0; jj < 4; ++jj)
#pragma unroll
                        for (int n = 0; n < 4; ++n)
                            sums[m * 4 + jj] +=
                                fexp2(fmaf(acc[m][n][jj], rl[n], -M0));
            }
        }
        ssCur = ssNext;
        ssNext = 0.f;
    }
#undef LOADSL
#undef CONVSL

    // ---- strip epilogue: reduce tracked rows across their 16 col-lanes ----
#pragma unroll
    for (int m = 0; m < 4; ++m)
#pragma unroll
        for (int jj = 0; jj < 4; ++jj) {
            float v = sums[m * 4 + jj];
            v += __shfl_xor(v, 1);
            v += __shfl_xor(v, 2);
            v += __shfl_xor(v, 4);
            v += __shfl_xor(v, 8);
            if (cl == 0) {
                const int r = wid * 64 + m * 16 + hi * 4 + jj;
                partials[s * B_ROWS + r] = v;
            }
        }
}

// ---------------- kernel 2: target-class cosine (fp32 exact) ----------------
__global__ __launch_bounds__(256) void tdot_kernel(const float* __restrict__ x,
                                                   const float* __restrict__ w,
                                                   const int* __restrict__ tgt,
                                                   const float* __restrict__ xrn,
                                                   float* __restrict__ tdot) {
    const int wid = threadIdx.x >> 6;
    const int lane = threadIdx.x & 63;
    const int b = blockIdx.x * 4 + wid;
    const int tg = tgt[b];
    const float* xr = x + (size_t)b * D_K + lane * 8;
    const float* wr = w + (size_t)tg * D_K + lane * 8;
    float4 xa = *(const float4*)xr;
    float4 xb = *(const float4*)(xr + 4);
    float4 wa = *(const float4*)wr;
    float4 wb = *(const float4*)(wr + 4);
    float xw = xa.x * wa.x + xa.y * wa.y + xa.z * wa.z + xa.w * wa.w
             + xb.x * wb.x + xb.y * wb.y + xb.z * wb.z + xb.w * wb.w;
    float ww = wa.x * wa.x + wa.y * wa.y + wa.z * wa.z + wa.w * wa.w
             + wb.x * wb.x + wb.y * wb.y + wb.z * wb.z + wb.w * wb.w;
#pragma unroll
    for (int m = 1; m < 64; m <<= 1) {
        xw += __shfl_xor(xw, m);
        ww += __shfl_xor(ww, m);
    }
    if (lane == 0) tdot[b] = xw * xrn[b] / sqrtf(ww);
}

// ---------------- kernel 3: per-row loss (margin fixup) + mean ----------------
__global__ __launch_bounds__(512) void final_kernel(const float* __restrict__ partials,
                                                    const float* __restrict__ tdot,
                                                    float* __restrict__ out) {
    const int b = threadIdx.x;   // 512 threads = 8 waves
    float s2 = 0.f;
    for (int s = 0; s < NSTRIP; ++s) s2 += partials[s * B_ROWS + b];
    const float cst = tdot[b];
    float c2 = 1.0f - cst * cst;
    c2 = fminf(fmaxf(c2, 0.0f), 1.0f);
    const float sine = sqrtf(c2);
    float phi = cst * COS_M - sine * SIN_M;
    phi = (cst > TH_C) ? phi : (cst - MM_C);
    const float Lt = cst * LOG2E_S;
    const float Lp = phi * LOG2E_S;
    // swap plain-target term for margin term in the denominator
    s2 = s2 - fexp2(Lt - M0) + fexp2(Lp - M0);
    float loss = LN2F * (M0 + log2f(s2) - Lp);
    loss += __shfl_xor(loss, 1);  loss += __shfl_xor(loss, 2);
    loss += __shfl_xor(loss, 4);  loss += __shfl_xor(loss, 8);
    loss += __shfl_xor(loss, 16); loss += __shfl_xor(loss, 32);
    __shared__ float sW[8];
    if ((b & 63) == 0) sW[b >> 6] = loss;
    __syncthreads();
    if (b == 0) {
        float tot = 0.f;
#pragma unroll
        for (int wv = 0; wv < 8; ++wv) tot += sW[wv];
        out[0] = tot * (1.0f / (float)B_ROWS);
    }
}

extern "C" void kernel_launch(void* const* d_in, const int* in_sizes, int n_in,
                              void* d_out, int out_size, void* d_ws, size_t ws_size,
                              hipStream_t stream) {
    const float* x = (const float*)d_in[0];
    const float* w = (const float*)d_in[1];
    const int* tgt = (const int*)d_in[2];
    float* out = (float*)d_out;

    char* ws = (char*)d_ws;
    size_t off = 0;
    unsigned char* xnb8 = (unsigned char*)(ws + off);
    off += (size_t)B_ROWS * D_K;                       // 256 KB
    off = (off + 255) & ~(size_t)255;
    float* xrn = (float*)(ws + off);
    off += B_ROWS * 4;
    off = (off + 255) & ~(size_t)255;
    float* partials = (float*)(ws + off);
    off += (size_t)NSTRIP * B_ROWS * 4;                // 448 KB
    off = (off + 255) & ~(size_t)255;
    float* tdot = (float*)(ws + off);
    off += B_ROWS * 4;

    rownorm8_kernel<<<B_ROWS / 4, 256, 0, stream>>>(x, (uint2*)xnb8, xrn, B_ROWS);
    tdot_kernel<<<B_ROWS / 4, 256, 0, stream>>>(x, w, tgt, xrn, tdot);
    gemm_fused512_kernel<<<NSTRIP, 512, 0, stream>>>(xnb8, w, partials);
    final_kernel<<<1, 512, 0, stream>>>(partials, tdot, out);
}